// Round 2
// baseline (5332.124 us; speedup 1.0000x reference)
//
#include <hip/hip_runtime.h>
#include <stdint.h>

// ---------------------------------------------------------------------------
// HMM forward: B=256, T=512, Q=1027, ALPHA=26.
// 16 clusters x 8 WGs (512 thr, 8 waves). Cluster c owns batches [16c,16c+16).
// WG j owns cols [128j,128j+128) (wave w: 16-col tile tg=8j+w); WG7 also owns
// cols 1024..1026 (tile 64, k-split over its 8 waves).
// Exchange buffer is stored directly in MFMA A-fragment layout:
//   chunk16B(kc, l) = { g[m=l&15][k=kc*32+(l>>4)*8+e] : e=0..7 }  (2112 chunks)
// so consumer staging + LDS writes + ds_read_b128 are all linear.
// Per-wave flags posted after a single vmcnt(0) (g + Sp partials together).
// Two-phase K pipeline: MFMA kc0-15 while kc16-32 loads are in flight.
// All cross-WG traffic uses sc0 sc1 (device-coherent, placement-independent).
// ---------------------------------------------------------------------------

#define Q     1027
#define TT    512
#define ALPH  26
#define KCH   33            // k-chunks of 32 (K padded to 1056)
#define NTILE 65            // 16-col tiles covering 1040
#define GIMG  (KCH*64*16)   // 33792 B per (cluster,parity) exchange image
#define NCL   16
#define WPC   8             // WGs per cluster
#define MB    16            // batches per cluster

typedef short  short8  __attribute__((ext_vector_type(8)));
typedef float  floatx4 __attribute__((ext_vector_type(4)));
typedef int    intx4   __attribute__((ext_vector_type(4)));

static constexpr size_t al512(size_t x) { return (x + 511) & ~size_t(511); }
static constexpr size_t OFF_APACK = 0;
static constexpr size_t SZ_APACK  = (size_t)NTILE * KCH * 64 * 16;   // 2,196,480
static constexpr size_t OFF_BSOFT = al512(OFF_APACK + SZ_APACK);
static constexpr size_t SZ_BSOFT  = (size_t)Q * ALPH * 4;
static constexpr size_t OFF_INIT  = al512(OFF_BSOFT + SZ_BSOFT);
static constexpr size_t OFF_AMAX  = al512(OFF_INIT + Q * 4);
static constexpr size_t OFF_AINV  = al512(OFF_AMAX + Q * 4);
static constexpr size_t OFF_GEX   = al512(OFF_AINV + Q * 4);
static constexpr size_t SZ_GEX    = (size_t)NCL * 2 * GIMG;          // 1,081,344
static constexpr size_t OFF_SP    = al512(OFF_GEX + SZ_GEX);         // [c][p][jw 64][m 16] f32
static constexpr size_t SZ_SP     = (size_t)NCL * 2 * 64 * MB * 4;   // 131,072
static constexpr size_t OFF_FLAGS = al512(OFF_SP + SZ_SP);           // [c][jw 64] int
static constexpr size_t SZ_FLAGS  = (size_t)NCL * 64 * 4;
static constexpr size_t WS_NEED   = OFF_FLAGS + SZ_FLAGS;            // ~3.53 MB
static constexpr size_t FWDSZ     = (size_t)256 * TT * Q;

__device__ __forceinline__ uint32_t f2bf(float f) {
  uint32_t u = __float_as_uint(f);
  return (u + 0x7fffu + ((u >> 16) & 1u)) >> 16;   // RNE
}

// ------------------------- prep kernels ------------------------------------

__global__ void k_zero(char* __restrict__ ws) {
  const int i = blockIdx.x * 256 + threadIdx.x;
  if (i < (int)(SZ_FLAGS / 4)) ((int*)(ws + OFF_FLAGS))[i] = 0;
}

__global__ void k_astats(const float* __restrict__ A, char* __restrict__ ws) {
  const int r = blockIdx.x, tid = threadIdx.x;
  const float* row = A + (size_t)r * Q;
  __shared__ float red[4], red2[4];
  float mx = -3.0e38f;
  for (int i = tid; i < Q; i += 256) mx = fmaxf(mx, row[i]);
#pragma unroll
  for (int d = 1; d < 64; d <<= 1) mx = fmaxf(mx, __shfl_xor(mx, d));
  if ((tid & 63) == 0) red[tid >> 6] = mx;
  __syncthreads();
  mx = fmaxf(fmaxf(red[0], red[1]), fmaxf(red[2], red[3]));
  float s = 0.f;
  for (int i = tid; i < Q; i += 256) s += expf(row[i] - mx);
#pragma unroll
  for (int d = 1; d < 64; d <<= 1) s += __shfl_xor(s, d);
  if ((tid & 63) == 0) red2[tid >> 6] = s;
  __syncthreads();
  s = red2[0] + red2[1] + red2[2] + red2[3];
  if (tid == 0) {
    *(float*)(ws + OFF_AMAX + (size_t)r * 4) = mx;
    *(float*)(ws + OFF_AINV + (size_t)r * 4) = 1.0f / s;
  }
}

__global__ void k_bsoft(const float* __restrict__ Bl, char* __restrict__ ws) {
  const int r = blockIdx.x, l = threadIdx.x;  // 64 threads
  float v = (l < ALPH) ? Bl[(size_t)r * ALPH + l] : -3.0e38f;
  float mx = v;
#pragma unroll
  for (int d = 1; d < 64; d <<= 1) mx = fmaxf(mx, __shfl_xor(mx, d));
  float e = (l < ALPH) ? expf(v - mx) : 0.f;
  float s = e;
#pragma unroll
  for (int d = 1; d < 64; d <<= 1) s += __shfl_xor(s, d);
  if (l < ALPH) *(float*)(ws + OFF_BSOFT + ((size_t)r * ALPH + l) * 4) = e / s;
}

__global__ void k_isoft(const float* __restrict__ il, char* __restrict__ ws) {
  const int tid = threadIdx.x;
  __shared__ float red[4], red2[4];
  float mx = -3.0e38f;
  for (int i = tid; i < Q; i += 256) mx = fmaxf(mx, il[i]);
#pragma unroll
  for (int d = 1; d < 64; d <<= 1) mx = fmaxf(mx, __shfl_xor(mx, d));
  if ((tid & 63) == 0) red[tid >> 6] = mx;
  __syncthreads();
  mx = fmaxf(fmaxf(red[0], red[1]), fmaxf(red[2], red[3]));
  float s = 0.f;
  for (int i = tid; i < Q; i += 256) s += expf(il[i] - mx);
#pragma unroll
  for (int d = 1; d < 64; d <<= 1) s += __shfl_xor(s, d);
  if ((tid & 63) == 0) red2[tid >> 6] = s;
  __syncthreads();
  s = red2[0] + red2[1] + red2[2] + red2[3];
  const float inv = 1.0f / s;
  for (int i = tid; i < Q; i += 256)
    *(float*)(ws + OFF_INIT + (size_t)i * 4) = expf(il[i] - mx) * inv;
}

// Apack[ntile][kc][lane][e] = A[k = kc*32 + (lane>>4)*8 + e][q = ntile*16 + (lane&15)]
__global__ void k_repack(const float* __restrict__ A, char* __restrict__ ws) {
  const int b = blockIdx.x;
  const int nt = b % NTILE, kc = b / NTILE;
  const int lane = threadIdx.x;
  const int q = nt * 16 + (lane & 15);
  const int kb = kc * 32 + (lane >> 4) * 8;
  union { short8 v; unsigned short u[8]; } pk;
#pragma unroll
  for (int e = 0; e < 8; ++e) {
    const int k = kb + e;
    float val = 0.f;
    if (k < Q && q < Q) {
      const float mxk = *(const float*)(ws + OFF_AMAX + (size_t)k * 4);
      const float ivk = *(const float*)(ws + OFF_AINV + (size_t)k * 4);
      val = expf(A[(size_t)k * Q + q] - mxk) * ivk;
    }
    pk.u[e] = (unsigned short)f2bf(val);
  }
  *(short8*)(ws + OFF_APACK + (((size_t)nt * KCH + kc) * 64 + lane) * 16) = pk.v;
}

// ------------------------- main persistent kernel --------------------------

__global__ __launch_bounds__(512) void k_main(const int* __restrict__ xin,
                                              char* __restrict__ ws,
                                              float* __restrict__ out) {
  const int bid = blockIdx.x;          // 128 WGs
  const int c = bid & 15, j = bid >> 4;
  const int tid = threadIdx.x;
  const int lane = tid & 63, w = tid >> 6;
  const int cL = lane & 15, g4 = lane >> 4;
  const int tg = 8 * j + w;            // 16-col tile index 0..63
  const int col0 = tg * 16;
  const bool jx = (j == 7);            // WG with the extra tile 64
  const bool own64 = (jx && w == 7);
  const int kc0x = 4 * w;              // tile64 k-split: wave w does kc [4w,4w+4) (+kc32 for w7)
  const int ncx = (w == 7) ? 5 : 4;
  const uint64_t wsu = (uint64_t)(uintptr_t)ws;

  __shared__ intx4   g_lds[2112];        // 33792 B, fragment order
  __shared__ float   B_lds[9][16][ALPH]; // 14976
  __shared__ uint8_t x_lds[MB * TT];     // 8192
  __shared__ floatx4 accx[7][64];        // 7168 (tile64 partials, waves 0..6)
  __shared__ float   init_lds[9][16];    // 576
  __shared__ float   SpL[2][16];         // 128

  // ---- stage per-WG constants ----
  for (int idx = tid; idx < MB * TT; idx += 512)
    x_lds[idx] = (uint8_t)xin[(size_t)(c * MB) * TT + idx];
  for (int idx = tid; idx < 9 * 16 * ALPH; idx += 512) {
    const int tl = idx / (16 * ALPH), rem = idx % (16 * ALPH);
    const int cc = rem / ALPH, a = rem % ALPH;
    const int grow = (tl < 8 ? 16 * (8 * j + tl) : 1024) + cc;
    B_lds[tl][cc][a] = (grow < Q) ? *(const float*)(ws + OFF_BSOFT + ((size_t)grow * ALPH + a) * 4) : 0.f;
  }
  for (int idx = tid; idx < 9 * 16; idx += 512) {
    const int tl = idx >> 4, cc = idx & 15;
    const int grow = (tl < 8 ? 16 * (8 * j + tl) : 1024) + cc;
    init_lds[tl][cc] = (grow < Q) ? *(const float*)(ws + OFF_INIT + (size_t)grow * 4) : 0.f;
  }

  // ---- persistent A fragments ----
  short8 af0[KCH];
#pragma unroll
  for (int kc = 0; kc < KCH; ++kc)
    af0[kc] = *(const short8*)(ws + OFF_APACK + (((size_t)tg * KCH + kc) * 64 + lane) * 16);
  short8 afx[5];
  if (jx) {
#pragma unroll
    for (int i = 0; i < 5; ++i) {
      if (i < ncx)
        afx[i] = *(const short8*)(ws + OFF_APACK + (((size_t)64 * KCH + kc0x + i) * 64 + lane) * 16);
    }
  }
  __syncthreads();

  float upc[4], upx[4] = {0.f, 0.f, 0.f, 0.f};
  float llacc = 0.f;

  // publish step TCUR: g slice (fragment layout) + Sp partials, one drain, wave flag
#define POSTSTEP(TCUR)                                                                    \
  do {                                                                                    \
    const int par_ = (TCUR) & 1;                                                          \
    const uint64_t gb_ = wsu + OFF_GEX + (size_t)(c * 2 + par_) * GIMG;                   \
    const uint64_t spb_ = wsu + OFF_SP + (size_t)(c * 2 + par_) * 4096;                   \
    const int sub_ = (2 * tg + (cL >> 3)) & 3;                                            \
    const uint64_t ga_ = gb_ + (size_t)((tg >> 1) * 1024) + (size_t)(16 * sub_) * 16 +    \
                         (size_t)(cL & 7) * 2;                                            \
    float tmp0_ = upc[0], tmp1_ = upc[1], tmp2_ = upc[2], tmp3_ = upc[3];                 \
    _Pragma("unroll") for (int r = 0; r < 4; ++r) {                                       \
      const int m_ = g4 * 4 + r;                                                          \
      uint32_t b_ = f2bf(upc[r]);                                                         \
      asm volatile("global_store_short %0, %1, off sc0 sc1" ::                            \
                   "v"(ga_ + (size_t)m_ * 16), "v"(b_) : "memory");                       \
    }                                                                                     \
    if (own64) {                                                                          \
      const uint64_t gx_ = gb_ + (size_t)(32 * 1024) + (size_t)((cL >> 3) * 16) * 16 +    \
                           (size_t)(cL & 7) * 2;                                          \
      _Pragma("unroll") for (int r = 0; r < 4; ++r) {                                     \
        const int m_ = g4 * 4 + r;                                                        \
        uint32_t b_ = f2bf(upx[r]);                                                       \
        asm volatile("global_store_short %0, %1, off sc0 sc1" ::                          \
                     "v"(gx_ + (size_t)m_ * 16), "v"(b_) : "memory");                     \
      }                                                                                   \
      tmp0_ += upx[0]; tmp1_ += upx[1]; tmp2_ += upx[2]; tmp3_ += upx[3];                 \
    }                                                                                     \
    _Pragma("unroll") for (int d_ = 1; d_ < 16; d_ <<= 1) {                               \
      tmp0_ += __shfl_xor(tmp0_, d_); tmp1_ += __shfl_xor(tmp1_, d_);                     \
      tmp2_ += __shfl_xor(tmp2_, d_); tmp3_ += __shfl_xor(tmp3_, d_);                     \
    }                                                                                     \
    if (cL == 0) {                                                                        \
      uint64_t sa_ = spb_ + (size_t)((8 * j + w) * 16 + g4 * 4) * 4;                      \
      asm volatile("global_store_dword %0, %1, off sc0 sc1" :: "v"(sa_), "v"(tmp0_) : "memory");     \
      asm volatile("global_store_dword %0, %1, off sc0 sc1" :: "v"(sa_ + 4), "v"(tmp1_) : "memory"); \
      asm volatile("global_store_dword %0, %1, off sc0 sc1" :: "v"(sa_ + 8), "v"(tmp2_) : "memory"); \
      asm volatile("global_store_dword %0, %1, off sc0 sc1" :: "v"(sa_ + 12), "v"(tmp3_) : "memory");\
    }                                                                                     \
    asm volatile("s_waitcnt vmcnt(0)" ::: "memory");                                      \
    __builtin_amdgcn_sched_barrier(0);                                                    \
    if (lane == 0) {                                                                      \
      uint64_t fa_ = wsu + OFF_FLAGS + (size_t)(c * 64 + 8 * j + w) * 4;                  \
      int fv_ = (TCUR) + 1;                                                               \
      asm volatile("global_store_dword %0, %1, off sc0 sc1" :: "v"(fa_), "v"(fv_) : "memory"); \
    }                                                                                     \
  } while (0)

  // per-wave wait: all 64 wave-flags of the cluster >= TGT
#define WAITF(TGT)                                                                        \
  do {                                                                                    \
    const uint64_t fa_ = wsu + OFF_FLAGS + (size_t)(c * 64 + lane) * 4;                   \
    for (;;) {                                                                            \
      int f_;                                                                             \
      asm volatile("global_load_dword %0, %1, off sc0 sc1\n\ts_waitcnt vmcnt(0)"          \
                   : "=v"(f_) : "v"(fa_) : "memory");                                     \
      if (__all(f_ >= (TGT))) break;                                                      \
      __builtin_amdgcn_s_sleep(1);                                                        \
    }                                                                                     \
  } while (0)

  // ---- step 0: u0 = E0 * init ----
#pragma unroll
  for (int r = 0; r < 4; ++r) {
    const int m = g4 * 4 + r;
    const int xm = x_lds[m * TT + 0];
    upc[r] = B_lds[w][cL][xm] * init_lds[w][cL];
    if (own64) upx[r] = B_lds[8][cL][xm] * init_lds[8][cL];
  }
  POSTSTEP(0);

  for (int t = 1; t < TT; ++t) {
    const int parp = (t - 1) & 1;
    WAITF(t);

    const uint64_t gb = wsu + OFF_GEX + (size_t)(c * 2 + parp) * GIMG;
    const uint64_t spb = wsu + OFF_SP + (size_t)(c * 2 + parp) * 4096;
    floatx4 sp0 = {0, 0, 0, 0}, sp1 = {0, 0, 0, 0};
    intx4 r0, r1, r2, r3, tl4;
    if (tid < 128) {  // waves 0,1: Sp region [jw 64][m 16] f32, 8 floats/thread
      uint64_t sa = spb + (size_t)tid * 32;
      asm volatile("global_load_dwordx4 %0, %1, off sc0 sc1" : "=v"(sp0) : "v"(sa) : "memory");
      asm volatile("global_load_dwordx4 %0, %1, off sc0 sc1" : "=v"(sp1) : "v"(sa + 16) : "memory");
    }
    if (tid < 64) {   // tail chunks 2048..2111
      asm volatile("global_load_dwordx4 %0, %1, off sc0 sc1"
                   : "=v"(tl4) : "v"(gb + (size_t)(2048 + tid) * 16) : "memory");
    }
    asm volatile("global_load_dwordx4 %0, %1, off sc0 sc1" : "=v"(r0) : "v"(gb + (size_t)tid * 16) : "memory");
    asm volatile("global_load_dwordx4 %0, %1, off sc0 sc1" : "=v"(r1) : "v"(gb + (size_t)(512 + tid) * 16) : "memory");
    asm volatile("global_load_dwordx4 %0, %1, off sc0 sc1" : "=v"(r2) : "v"(gb + (size_t)(1024 + tid) * 16) : "memory");
    asm volatile("global_load_dwordx4 %0, %1, off sc0 sc1" : "=v"(r3) : "v"(gb + (size_t)(1536 + tid) * 16) : "memory");
    asm volatile("s_waitcnt vmcnt(2)" ::: "memory");   // r0,r1 (+Sp,tail) arrived
    __builtin_amdgcn_sched_barrier(0);
    g_lds[tid] = r0;
    g_lds[512 + tid] = r1;
    if (tid < 128) {  // reduce Sp over jw (lane bits 1..5)
#pragma unroll
      for (int d = 2; d < 64; d <<= 1) {
#pragma unroll
        for (int e = 0; e < 4; ++e) { sp0[e] += __shfl_xor(sp0[e], d); sp1[e] += __shfl_xor(sp1[e], d); }
      }
      if (lane < 2) {
        const int mb = (lane & 1) * 8;
#pragma unroll
        for (int e = 0; e < 4; ++e) { SpL[w][mb + e] = sp0[e]; SpL[w][mb + 4 + e] = sp1[e]; }
      }
    }
    __syncthreads();  // sync1: chunks 0..1023 (kc 0..15) + SpL ready

    // phase A: MFMA kc 0..15
    floatx4 a0v = {0, 0, 0, 0}, a1v = {0, 0, 0, 0}, axv = {0, 0, 0, 0};
    const char* gl = (const char*)g_lds;
#pragma unroll
    for (int kc = 0; kc < 16; ++kc) {
      short8 gf = *(const short8*)(gl + (kc * 64 + lane) * 16);
      if (kc & 1) a1v = __builtin_amdgcn_mfma_f32_16x16x32_bf16(gf, af0[kc], a1v, 0, 0, 0);
      else        a0v = __builtin_amdgcn_mfma_f32_16x16x32_bf16(gf, af0[kc], a0v, 0, 0, 0);
    }
    if (jx && kc0x < 16) {  // tile64 share for waves 0..3
#pragma unroll
      for (int i = 0; i < 4; ++i) {
        short8 gf = *(const short8*)(gl + ((kc0x + i) * 64 + lane) * 16);
        axv = __builtin_amdgcn_mfma_f32_16x16x32_bf16(gf, afx[i], axv, 0, 0, 0);
      }
    }
    asm volatile("s_waitcnt vmcnt(0)" ::: "memory");
    __builtin_amdgcn_sched_barrier(0);
    g_lds[1024 + tid] = r2;
    g_lds[1536 + tid] = r3;
    if (tid < 64) g_lds[2048 + tid] = tl4;
    __syncthreads();  // sync2: chunks 1024..2111 (kc 16..32) ready

    // S'_{t-1}, fwd_{t-1} out-writes (drained later by POSTSTEP's vmcnt(0))
    float invS[4];
#pragma unroll
    for (int r = 0; r < 4; ++r) {
      const int m = g4 * 4 + r;
      invS[r] = 1.0f / (SpL[0][m] + SpL[1][m]);
    }
    if (j == 0 && w == 0 && lane < 16) llacc += logf(SpL[0][lane] + SpL[1][lane]);
#pragma unroll
    for (int r = 0; r < 4; ++r) {
      const int m = g4 * 4 + r;
      const size_t ob = ((size_t)(c * MB + m) * TT + (t - 1)) * Q;
      __builtin_nontemporal_store(upc[r] * invS[r], out + ob + col0 + cL);
      if (own64 && cL < 3)
        __builtin_nontemporal_store(upx[r] * invS[r], out + ob + 1024 + cL);
    }

    // phase B: MFMA kc 16..32
#pragma unroll
    for (int kc = 16; kc < KCH; ++kc) {
      short8 gf = *(const short8*)(gl + (kc * 64 + lane) * 16);
      if (kc & 1) a1v = __builtin_amdgcn_mfma_f32_16x16x32_bf16(gf, af0[kc], a1v, 0, 0, 0);
      else        a0v = __builtin_amdgcn_mfma_f32_16x16x32_bf16(gf, af0[kc], a0v, 0, 0, 0);
    }
    if (jx && kc0x >= 16) {  // tile64 share for waves 4..7
#pragma unroll
      for (int i = 0; i < 5; ++i) {
        if (i < ncx) {
          short8 gf = *(const short8*)(gl + ((kc0x + i) * 64 + lane) * 16);
          axv = __builtin_amdgcn_mfma_f32_16x16x32_bf16(gf, afx[i], axv, 0, 0, 0);
        }
      }
    }
    float rx[4] = {0.f, 0.f, 0.f, 0.f};
    if (jx) {
      if (w < 7) accx[w][lane] = axv;
      __syncthreads();  // uniform within WG 7
      if (own64) {
#pragma unroll
        for (int r = 0; r < 4; ++r) {
          rx[r] = axv[r];
#pragma unroll
          for (int i = 0; i < 7; ++i) rx[r] += accx[i][lane][r];
        }
      }
    }

    // epilogue: u~_t = E_t * (g@A) * invS'
#pragma unroll
    for (int r = 0; r < 4; ++r) {
      const int m = g4 * 4 + r;
      const int xm = x_lds[m * TT + t];
      upc[r] = (a0v[r] + a1v[r]) * B_lds[w][cL][xm] * invS[r];
      if (own64) upx[r] = rx[r] * B_lds[8][cL][xm] * invS[r];
    }
    POSTSTEP(t);
  }

  // ---- final: S'_511, fwd_511, loglik ----
  WAITF(TT);
  {
    const int parp = (TT - 1) & 1;
    const uint64_t spb = wsu + OFF_SP + (size_t)(c * 2 + parp) * 4096;
    floatx4 sp0 = {0, 0, 0, 0}, sp1 = {0, 0, 0, 0};
    if (tid < 128) {
      uint64_t sa = spb + (size_t)tid * 32;
      asm volatile("global_load_dwordx4 %0, %1, off sc0 sc1" : "=v"(sp0) : "v"(sa) : "memory");
      asm volatile("global_load_dwordx4 %0, %1, off sc0 sc1" : "=v"(sp1) : "v"(sa + 16) : "memory");
      asm volatile("s_waitcnt vmcnt(0)" ::: "memory");
      __builtin_amdgcn_sched_barrier(0);
#pragma unroll
      for (int d = 2; d < 64; d <<= 1) {
#pragma unroll
        for (int e = 0; e < 4; ++e) { sp0[e] += __shfl_xor(sp0[e], d); sp1[e] += __shfl_xor(sp1[e], d); }
      }
      if (lane < 2) {
        const int mb = (lane & 1) * 8;
#pragma unroll
        for (int e = 0; e < 4; ++e) { SpL[w][mb + e] = sp0[e]; SpL[w][mb + 4 + e] = sp1[e]; }
      }
    }
    __syncthreads();
    float invS[4];
#pragma unroll
    for (int r = 0; r < 4; ++r) {
      const int m = g4 * 4 + r;
      invS[r] = 1.0f / (SpL[0][m] + SpL[1][m]);
    }
    if (j == 0 && w == 0 && lane < 16) llacc += logf(SpL[0][lane] + SpL[1][lane]);
#pragma unroll
    for (int r = 0; r < 4; ++r) {
      const int m = g4 * 4 + r;
      const size_t ob = ((size_t)(c * MB + m) * TT + (TT - 1)) * Q;
      __builtin_nontemporal_store(upc[r] * invS[r], out + ob + col0 + cL);
      if (own64 && cL < 3)
        __builtin_nontemporal_store(upx[r] * invS[r], out + ob + 1024 + cL);
    }
    if (j == 0 && w == 0 && lane < 16) out[FWDSZ + (size_t)c * MB + lane] = llacc;
  }
}

// ------------------------- launch ------------------------------------------

extern "C" void kernel_launch(void* const* d_in, const int* in_sizes, int n_in,
                              void* d_out, int out_size, void* d_ws, size_t ws_size,
                              hipStream_t stream) {
  const int*   x    = (const int*)d_in[0];
  const float* Alog = (const float*)d_in[1];
  const float* Blog = (const float*)d_in[2];
  const float* ilog = (const float*)d_in[3];
  char*  ws  = (char*)d_ws;
  float* out = (float*)d_out;
  if (ws_size < WS_NEED) return;  // need ~3.54 MB scratch

  hipLaunchKernelGGL(k_zero,   dim3(4),           dim3(256), 0, stream, ws);
  hipLaunchKernelGGL(k_astats, dim3(Q),           dim3(256), 0, stream, Alog, ws);
  hipLaunchKernelGGL(k_bsoft,  dim3(Q),           dim3(64),  0, stream, Blog, ws);
  hipLaunchKernelGGL(k_isoft,  dim3(1),           dim3(256), 0, stream, ilog, ws);
  hipLaunchKernelGGL(k_repack, dim3(NTILE * KCH), dim3(64),  0, stream, Alog, ws);
  hipLaunchKernelGGL(k_main,   dim3(128),         dim3(512), 0, stream, x, ws, out);
}

// Round 3
// 3004.023 us; speedup vs baseline: 1.7750x; 1.7750x over previous
//
#include <hip/hip_runtime.h>
#include <stdint.h>

// ---------------------------------------------------------------------------
// HMM forward: B=256, T=512, Q=1027, ALPHA=26.
// 16 clusters x 8 WGs (256 thr, 4 waves). Cluster c owns batches [16c,16c+16).
// Wave wgi=4j+w owns 16-col tiles {2*wgi, 2*wgi+1} (A-fragments in registers,
// 264 VGPRs); WG7 additionally owns cols 1024..1026 (tile 64, k-split over
// its 4 waves). Exchange buffer in MFMA A-fragment layout:
//   chunk16B(kc,l) = { g[m=l&15][k=kc*32+(l>>4)*8+e] : e=0..7 }, 2112 chunks.
// Per-wave Sp partials + per-wave flags; ONE vmcnt(0) drain per step, ONE
// __syncthreads per step (plus one extra inside WG7 for the tile64 reduce).
// All cross-WG traffic uses sc0 sc1 (device-coherent, placement-independent).
// ---------------------------------------------------------------------------

#define Q     1027
#define TT    512
#define ALPH  26
#define KCH   33              // k-chunks of 32 (K padded to 1056)
#define NTILE 65              // 16-col tiles covering 1040
#define NCHK  (KCH*64)        // 2112 chunks
#define GIMG  (NCHK*16)       // 33792 B per (cluster,parity) image
#define NCL   16
#define WPC   8               // WGs per cluster
#define WVC   32              // waves per cluster
#define MB    16              // batches per cluster

typedef short  short8  __attribute__((ext_vector_type(8)));
typedef float  floatx4 __attribute__((ext_vector_type(4)));
typedef int    intx4   __attribute__((ext_vector_type(4)));

static constexpr size_t al512(size_t x) { return (x + 511) & ~size_t(511); }
static constexpr size_t OFF_APACK = 0;
static constexpr size_t SZ_APACK  = (size_t)NTILE * KCH * 64 * 16;   // 2,196,480
static constexpr size_t OFF_BSOFT = al512(OFF_APACK + SZ_APACK);
static constexpr size_t SZ_BSOFT  = (size_t)Q * ALPH * 4;
static constexpr size_t OFF_INIT  = al512(OFF_BSOFT + SZ_BSOFT);
static constexpr size_t OFF_AMAX  = al512(OFF_INIT + Q * 4);
static constexpr size_t OFF_AINV  = al512(OFF_AMAX + Q * 4);
static constexpr size_t OFF_GEX   = al512(OFF_AINV + Q * 4);
static constexpr size_t SZ_GEX    = (size_t)NCL * 2 * GIMG;          // 1,081,344
static constexpr size_t OFF_SP    = al512(OFF_GEX + SZ_GEX);         // [c][p][wgi 32][m 16] f32
static constexpr size_t SZ_SP     = (size_t)NCL * 2 * WVC * MB * 4;  // 65,536
static constexpr size_t OFF_FLAGS = al512(OFF_SP + SZ_SP);           // [c][wgi 32] int
static constexpr size_t SZ_FLAGS  = (size_t)NCL * WVC * 4;           // 2,048
static constexpr size_t WS_NEED   = OFF_FLAGS + SZ_FLAGS;            // ~3.36 MB
static constexpr size_t FWDSZ     = (size_t)256 * TT * Q;

__device__ __forceinline__ uint32_t f2bf(float f) {
  uint32_t u = __float_as_uint(f);
  return (u + 0x7fffu + ((u >> 16) & 1u)) >> 16;   // RNE
}

// ------------------------- prep kernels ------------------------------------

__global__ void k_zero(char* __restrict__ ws) {
  for (int i = threadIdx.x; i < (int)(SZ_FLAGS / 4); i += 256)
    ((int*)(ws + OFF_FLAGS))[i] = 0;
}

__global__ void k_astats(const float* __restrict__ A, char* __restrict__ ws) {
  const int r = blockIdx.x, tid = threadIdx.x;
  const float* row = A + (size_t)r * Q;
  __shared__ float red[4], red2[4];
  float mx = -3.0e38f;
  for (int i = tid; i < Q; i += 256) mx = fmaxf(mx, row[i]);
#pragma unroll
  for (int d = 1; d < 64; d <<= 1) mx = fmaxf(mx, __shfl_xor(mx, d));
  if ((tid & 63) == 0) red[tid >> 6] = mx;
  __syncthreads();
  mx = fmaxf(fmaxf(red[0], red[1]), fmaxf(red[2], red[3]));
  float s = 0.f;
  for (int i = tid; i < Q; i += 256) s += expf(row[i] - mx);
#pragma unroll
  for (int d = 1; d < 64; d <<= 1) s += __shfl_xor(s, d);
  if ((tid & 63) == 0) red2[tid >> 6] = s;
  __syncthreads();
  s = red2[0] + red2[1] + red2[2] + red2[3];
  if (tid == 0) {
    *(float*)(ws + OFF_AMAX + (size_t)r * 4) = mx;
    *(float*)(ws + OFF_AINV + (size_t)r * 4) = 1.0f / s;
  }
}

__global__ void k_bsoft(const float* __restrict__ Bl, char* __restrict__ ws) {
  const int r = blockIdx.x, l = threadIdx.x;  // 64 threads
  float v = (l < ALPH) ? Bl[(size_t)r * ALPH + l] : -3.0e38f;
  float mx = v;
#pragma unroll
  for (int d = 1; d < 64; d <<= 1) mx = fmaxf(mx, __shfl_xor(mx, d));
  float e = (l < ALPH) ? expf(v - mx) : 0.f;
  float s = e;
#pragma unroll
  for (int d = 1; d < 64; d <<= 1) s += __shfl_xor(s, d);
  if (l < ALPH) *(float*)(ws + OFF_BSOFT + ((size_t)r * ALPH + l) * 4) = e / s;
}

__global__ void k_isoft(const float* __restrict__ il, char* __restrict__ ws) {
  const int tid = threadIdx.x;
  __shared__ float red[4], red2[4];
  float mx = -3.0e38f;
  for (int i = tid; i < Q; i += 256) mx = fmaxf(mx, il[i]);
#pragma unroll
  for (int d = 1; d < 64; d <<= 1) mx = fmaxf(mx, __shfl_xor(mx, d));
  if ((tid & 63) == 0) red[tid >> 6] = mx;
  __syncthreads();
  mx = fmaxf(fmaxf(red[0], red[1]), fmaxf(red[2], red[3]));
  float s = 0.f;
  for (int i = tid; i < Q; i += 256) s += expf(il[i] - mx);
#pragma unroll
  for (int d = 1; d < 64; d <<= 1) s += __shfl_xor(s, d);
  if ((tid & 63) == 0) red2[tid >> 6] = s;
  __syncthreads();
  s = red2[0] + red2[1] + red2[2] + red2[3];
  const float inv = 1.0f / s;
  for (int i = tid; i < Q; i += 256)
    *(float*)(ws + OFF_INIT + (size_t)i * 4) = expf(il[i] - mx) * inv;
}

// Apack[ntile][kc][lane][e] = A[k = kc*32 + (lane>>4)*8 + e][q = ntile*16 + (lane&15)]
__global__ void k_repack(const float* __restrict__ A, char* __restrict__ ws) {
  const int b = blockIdx.x;
  const int nt = b % NTILE, kc = b / NTILE;
  const int lane = threadIdx.x;
  const int q = nt * 16 + (lane & 15);
  const int kb = kc * 32 + (lane >> 4) * 8;
  union { short8 v; unsigned short u[8]; } pk;
#pragma unroll
  for (int e = 0; e < 8; ++e) {
    const int k = kb + e;
    float val = 0.f;
    if (k < Q && q < Q) {
      const float mxk = *(const float*)(ws + OFF_AMAX + (size_t)k * 4);
      const float ivk = *(const float*)(ws + OFF_AINV + (size_t)k * 4);
      val = expf(A[(size_t)k * Q + q] - mxk) * ivk;
    }
    pk.u[e] = (unsigned short)f2bf(val);
  }
  *(short8*)(ws + OFF_APACK + (((size_t)nt * KCH + kc) * 64 + lane) * 16) = pk.v;
}

// ------------------------- main persistent kernel --------------------------

__global__ __launch_bounds__(256, 1) void k_main(const int* __restrict__ xin,
                                                 char* __restrict__ ws,
                                                 float* __restrict__ out) {
  const int bid = blockIdx.x;          // 128 WGs
  const int c = bid & 15, j = bid >> 4;  // j 0..7
  const int tid = threadIdx.x;
  const int lane = tid & 63, w = tid >> 6;
  const int cL = lane & 15, g4 = lane >> 4;
  const int wgi = 4 * j + w;           // wave index in cluster, 0..31
  const int t0 = 2 * wgi;              // this wave's tiles: t0, t0+1
  const bool jx = (j == 7);
  const bool own64 = (jx && w == 3);
  const uint64_t wsu = (uint64_t)(uintptr_t)ws;

  __shared__ intx4   g_lds[NCHK];        // 33792 B, fragment order
  __shared__ float   B_lds[9][16][ALPH]; // 14976
  __shared__ uint8_t x_lds[MB * TT];     // 8192
  __shared__ floatx4 accx[4][64];        // 4096 (tile64 partials, WG7)
  __shared__ float   init_lds[9][16];    // 576
  __shared__ float   SpL[16];            // 64

  // ---- stage per-WG constants ----
  for (int idx = tid; idx < MB * TT; idx += 256)
    x_lds[idx] = (uint8_t)xin[(size_t)(c * MB) * TT + idx];
  for (int idx = tid; idx < 9 * 16 * ALPH; idx += 256) {
    const int tl = idx / (16 * ALPH), rem = idx % (16 * ALPH);
    const int cc = rem / ALPH, a = rem % ALPH;
    const int grow = (tl < 8 ? 16 * (8 * j + tl) : 1024) + cc;
    B_lds[tl][cc][a] = (grow < Q) ? *(const float*)(ws + OFF_BSOFT + ((size_t)grow * ALPH + a) * 4) : 0.f;
  }
  for (int idx = tid; idx < 9 * 16; idx += 256) {
    const int tl = idx >> 4, cc = idx & 15;
    const int grow = (tl < 8 ? 16 * (8 * j + tl) : 1024) + cc;
    init_lds[tl][cc] = (grow < Q) ? *(const float*)(ws + OFF_INIT + (size_t)grow * 4) : 0.f;
  }

  // ---- persistent A fragments: 2 tiles/wave (+ tile64 k-split in WG7) ----
  short8 af[2][KCH];
#pragma unroll
  for (int i = 0; i < 2; ++i)
#pragma unroll
    for (int kc = 0; kc < KCH; ++kc)
      af[i][kc] = *(const short8*)(ws + OFF_APACK + (((size_t)(t0 + i) * KCH + kc) * 64 + lane) * 16);
  short8 afx[9];
  if (jx) {
#pragma unroll
    for (int i = 0; i < 9; ++i) {
      if (i < 8 || w == 3) {
        const int kc = 8 * w + i;   // w3 also gets kc=32
        afx[i] = *(const short8*)(ws + OFF_APACK + (((size_t)64 * KCH + kc) * 64 + lane) * 16);
      }
    }
  }
  __syncthreads();

  float up[2][4], upx[4] = {0.f, 0.f, 0.f, 0.f};
  float llacc = 0.f;

  // publish step TCUR: g fragments + per-wave Sp partial, ONE drain, wave flag
#define POSTSTEP(TCUR)                                                                    \
  do {                                                                                    \
    const int par_ = (TCUR) & 1;                                                          \
    const uint64_t gb_ = wsu + OFF_GEX + (size_t)(c * 2 + par_) * GIMG;                   \
    const uint64_t b0_ = gb_ + (size_t)wgi * 1024 + (size_t)(cL >> 3) * 256 +             \
                         (size_t)(cL & 7) * 2;                                            \
    float s0_, s1_, s2_, s3_;                                                             \
    _Pragma("unroll") for (int r_ = 0; r_ < 4; ++r_) {                                    \
      const int m_ = g4 * 4 + r_;                                                         \
      uint32_t v0_ = f2bf(up[0][r_]);                                                     \
      uint32_t v1_ = f2bf(up[1][r_]);                                                     \
      asm volatile("global_store_short %0, %1, off sc0 sc1" ::                            \
                   "v"(b0_ + (size_t)m_ * 16), "v"(v0_) : "memory");                      \
      asm volatile("global_store_short %0, %1, off sc0 sc1" ::                            \
                   "v"(b0_ + 512 + (size_t)m_ * 16), "v"(v1_) : "memory");                \
    }                                                                                     \
    s0_ = up[0][0] + up[1][0]; s1_ = up[0][1] + up[1][1];                                 \
    s2_ = up[0][2] + up[1][2]; s3_ = up[0][3] + up[1][3];                                 \
    if (own64) {                                                                          \
      const uint64_t bx_ = gb_ + (size_t)2048 * 16 + (size_t)(cL >> 3) * 256 +            \
                           (size_t)(cL & 7) * 2;                                          \
      _Pragma("unroll") for (int r_ = 0; r_ < 4; ++r_) {                                  \
        const int m_ = g4 * 4 + r_;                                                       \
        uint32_t v_ = f2bf(upx[r_]);                                                      \
        asm volatile("global_store_short %0, %1, off sc0 sc1" ::                          \
                     "v"(bx_ + (size_t)m_ * 16), "v"(v_) : "memory");                     \
      }                                                                                   \
      s0_ += upx[0]; s1_ += upx[1]; s2_ += upx[2]; s3_ += upx[3];                         \
    }                                                                                     \
    _Pragma("unroll") for (int d_ = 1; d_ < 16; d_ <<= 1) {                               \
      s0_ += __shfl_xor(s0_, d_); s1_ += __shfl_xor(s1_, d_);                             \
      s2_ += __shfl_xor(s2_, d_); s3_ += __shfl_xor(s3_, d_);                             \
    }                                                                                     \
    if (cL == 0) {                                                                        \
      floatx4 sv_; sv_[0] = s0_; sv_[1] = s1_; sv_[2] = s2_; sv_[3] = s3_;                \
      uint64_t sa_ = wsu + OFF_SP + (size_t)(c * 2 + par_) * 2048 +                       \
                     (size_t)(wgi * 16 + g4 * 4) * 4;                                     \
      asm volatile("global_store_dwordx4 %0, %1, off sc0 sc1" ::                          \
                   "v"(sa_), "v"(sv_) : "memory");                                        \
    }                                                                                     \
    asm volatile("s_waitcnt vmcnt(0)" ::: "memory");                                      \
    __builtin_amdgcn_sched_barrier(0);                                                    \
    if (lane == 0) {                                                                      \
      uint64_t fa_ = wsu + OFF_FLAGS + (size_t)(c * WVC + wgi) * 4;                       \
      int fv_ = (TCUR) + 1;                                                               \
      asm volatile("global_store_dword %0, %1, off sc0 sc1" :: "v"(fa_), "v"(fv_)         \
                   : "memory");                                                           \
    }                                                                                     \
  } while (0)

  // per-wave wait: all 32 wave-flags of the cluster >= TGT (tight spin)
#define WAITF(TGT)                                                                        \
  do {                                                                                    \
    const uint64_t fa_ = wsu + OFF_FLAGS + (size_t)(c * WVC + (lane & 31)) * 4;           \
    for (;;) {                                                                            \
      int f_;                                                                             \
      asm volatile("global_load_dword %0, %1, off sc0 sc1\n\ts_waitcnt vmcnt(0)"          \
                   : "=v"(f_) : "v"(fa_) : "memory");                                     \
      if (__all(f_ >= (TGT))) break;                                                      \
    }                                                                                     \
  } while (0)

  // ---- step 0: u0 = E0 * init ----
#pragma unroll
  for (int r = 0; r < 4; ++r) {
    const int m = g4 * 4 + r;
    const int xm = x_lds[m * TT + 0];
    up[0][r] = B_lds[2 * w][cL][xm] * init_lds[2 * w][cL];
    up[1][r] = B_lds[2 * w + 1][cL][xm] * init_lds[2 * w + 1][cL];
    if (own64) upx[r] = B_lds[8][cL][xm] * init_lds[8][cL];
  }
  POSTSTEP(0);

  for (int t = 1; t < TT; ++t) {
    const int parp = (t - 1) & 1;
    WAITF(t);

    // stage g_{t-1} (fragment layout, linear) + Sp partials (wave 0 only)
    const uint64_t gb = wsu + OFF_GEX + (size_t)(c * 2 + parp) * GIMG;
    intx4 sg[8];
#pragma unroll
    for (int i = 0; i < 8; ++i) {
      asm volatile("global_load_dwordx4 %0, %1, off sc0 sc1"
                   : "=v"(sg[i]) : "v"(gb + (size_t)(i * 256 + tid) * 16) : "memory");
    }
    intx4 tl4;
    if (w == 3) {
      asm volatile("global_load_dwordx4 %0, %1, off sc0 sc1"
                   : "=v"(tl4) : "v"(gb + (size_t)(2048 + lane) * 16) : "memory");
    }
    floatx4 sp0, sp1;
    if (w == 0) {
      const uint64_t sa = wsu + OFF_SP + (size_t)(c * 2 + parp) * 2048 + (size_t)lane * 32;
      asm volatile("global_load_dwordx4 %0, %1, off sc0 sc1" : "=v"(sp0) : "v"(sa) : "memory");
      asm volatile("global_load_dwordx4 %0, %1, off sc0 sc1" : "=v"(sp1) : "v"(sa + 16) : "memory");
    }
    asm volatile("s_waitcnt vmcnt(0)" ::: "memory");
    __builtin_amdgcn_sched_barrier(0);
#pragma unroll
    for (int i = 0; i < 8; ++i) g_lds[i * 256 + tid] = sg[i];
    if (w == 3) g_lds[2048 + lane] = tl4;
    if (w == 0) {
      // lane l holds Sp[wgi=l>>1][(l&1)*8 + e]; reduce over wgi (lane bits 1..5)
#pragma unroll
      for (int d = 2; d < 64; d <<= 1) {
#pragma unroll
        for (int e = 0; e < 4; ++e) { sp0[e] += __shfl_xor(sp0[e], d); sp1[e] += __shfl_xor(sp1[e], d); }
      }
      if (lane < 2) {
        *(floatx4*)&SpL[lane * 8] = sp0;
        *(floatx4*)&SpL[lane * 8 + 4] = sp1;
      }
    }
    __syncthreads();  // g_lds + SpL ready

    // S_{t-1}: normalize & write fwd_{t-1} (drained by POSTSTEP's vmcnt(0))
    float invS[4];
#pragma unroll
    for (int r = 0; r < 4; ++r) invS[r] = 1.0f / SpL[g4 * 4 + r];
    if (j == 0 && w == 0 && lane < 16) llacc += logf(SpL[lane]);
#pragma unroll
    for (int r = 0; r < 4; ++r) {
      const int m = g4 * 4 + r;
      const size_t ob = ((size_t)(c * MB + m) * TT + (t - 1)) * Q;
      __builtin_nontemporal_store(up[0][r] * invS[r], out + ob + t0 * 16 + cL);
      __builtin_nontemporal_store(up[1][r] * invS[r], out + ob + t0 * 16 + 16 + cL);
      if (own64 && cL < 3)
        __builtin_nontemporal_store(upx[r] * invS[r], out + ob + 1024 + cL);
    }

    // matvec: both tiles share each g fragment read
    floatx4 acc[2][2] = {{{0,0,0,0},{0,0,0,0}},{{0,0,0,0},{0,0,0,0}}};
#pragma unroll
    for (int kc = 0; kc < KCH; ++kc) {
      const short8 gf = *(const short8*)&g_lds[kc * 64 + lane];
      acc[0][kc & 1] = __builtin_amdgcn_mfma_f32_16x16x32_bf16(gf, af[0][kc], acc[0][kc & 1], 0, 0, 0);
      acc[1][kc & 1] = __builtin_amdgcn_mfma_f32_16x16x32_bf16(gf, af[1][kc], acc[1][kc & 1], 0, 0, 0);
    }
    float rx[4];
    if (jx) {  // tile64: k-split over WG7's 4 waves
      floatx4 ax = {0, 0, 0, 0};
#pragma unroll
      for (int i = 0; i < 9; ++i) {
        if (i < 8 || w == 3) {
          const int kc = 8 * w + i;
          const short8 gf = *(const short8*)&g_lds[kc * 64 + lane];
          ax = __builtin_amdgcn_mfma_f32_16x16x32_bf16(gf, afx[i], ax, 0, 0, 0);
        }
      }
      accx[w][lane] = ax;
      __syncthreads();  // uniform within WG7
      if (own64) {
#pragma unroll
        for (int r = 0; r < 4; ++r)
          rx[r] = accx[0][lane][r] + accx[1][lane][r] + accx[2][lane][r] + accx[3][lane][r];
      }
    }

    // epilogue: u~_t = E_t * (g@A) * invS
#pragma unroll
    for (int r = 0; r < 4; ++r) {
      const int m = g4 * 4 + r;
      const int xm = x_lds[m * TT + t];
      up[0][r] = (acc[0][0][r] + acc[0][1][r]) * B_lds[2 * w][cL][xm] * invS[r];
      up[1][r] = (acc[1][0][r] + acc[1][1][r]) * B_lds[2 * w + 1][cL][xm] * invS[r];
      if (own64) upx[r] = rx[r] * B_lds[8][cL][xm] * invS[r];
    }
    POSTSTEP(t);
  }

  // ---- final: S_511, fwd_511, loglik ----
  WAITF(TT);
  {
    const int parp = (TT - 1) & 1;
    floatx4 sp0, sp1;
    if (w == 0) {
      const uint64_t sa = wsu + OFF_SP + (size_t)(c * 2 + parp) * 2048 + (size_t)lane * 32;
      asm volatile("global_load_dwordx4 %0, %1, off sc0 sc1" : "=v"(sp0) : "v"(sa) : "memory");
      asm volatile("global_load_dwordx4 %0, %1, off sc0 sc1\n\ts_waitcnt vmcnt(0)"
                   : "=v"(sp1) : "v"(sa + 16) : "memory");
      __builtin_amdgcn_sched_barrier(0);
#pragma unroll
      for (int d = 2; d < 64; d <<= 1) {
#pragma unroll
        for (int e = 0; e < 4; ++e) { sp0[e] += __shfl_xor(sp0[e], d); sp1[e] += __shfl_xor(sp1[e], d); }
      }
      if (lane < 2) {
        *(floatx4*)&SpL[lane * 8] = sp0;
        *(floatx4*)&SpL[lane * 8 + 4] = sp1;
      }
    }
    __syncthreads();
    float invS[4];
#pragma unroll
    for (int r = 0; r < 4; ++r) invS[r] = 1.0f / SpL[g4 * 4 + r];
    if (j == 0 && w == 0 && lane < 16) llacc += logf(SpL[lane]);
#pragma unroll
    for (int r = 0; r < 4; ++r) {
      const int m = g4 * 4 + r;
      const size_t ob = ((size_t)(c * MB + m) * TT + (TT - 1)) * Q;
      __builtin_nontemporal_store(up[0][r] * invS[r], out + ob + t0 * 16 + cL);
      __builtin_nontemporal_store(up[1][r] * invS[r], out + ob + t0 * 16 + 16 + cL);
      if (own64 && cL < 3)
        __builtin_nontemporal_store(upx[r] * invS[r], out + ob + 1024 + cL);
    }
    if (j == 0 && w == 0 && lane < 16) out[FWDSZ + (size_t)c * MB + lane] = llacc;
  }
}

// ------------------------- launch ------------------------------------------

extern "C" void kernel_launch(void* const* d_in, const int* in_sizes, int n_in,
                              void* d_out, int out_size, void* d_ws, size_t ws_size,
                              hipStream_t stream) {
  const int*   x    = (const int*)d_in[0];
  const float* Alog = (const float*)d_in[1];
  const float* Blog = (const float*)d_in[2];
  const float* ilog = (const float*)d_in[3];
  char*  ws  = (char*)d_ws;
  float* out = (float*)d_out;
  if (ws_size < WS_NEED) return;  // need ~3.4 MB scratch

  hipLaunchKernelGGL(k_zero,   dim3(1),           dim3(256), 0, stream, ws);
  hipLaunchKernelGGL(k_astats, dim3(Q),           dim3(256), 0, stream, Alog, ws);
  hipLaunchKernelGGL(k_bsoft,  dim3(Q),           dim3(64),  0, stream, Blog, ws);
  hipLaunchKernelGGL(k_isoft,  dim3(1),           dim3(256), 0, stream, ilog, ws);
  hipLaunchKernelGGL(k_repack, dim3(NTILE * KCH), dim3(64),  0, stream, Alog, ws);
  hipLaunchKernelGGL(k_main,   dim3(NCL * WPC),   dim3(256), 0, stream, x, ws, out);
}